// Round 1
// baseline (376.803 us; speedup 1.0000x reference)
//
#include <hip/hip_runtime.h>

// ---------------------------------------------------------------------------
// EquivariantProductBasisBlock (MACE symmetric contraction + gate + linear)
// N=10000 nodes, C=128 channels, D=9 (0e+1o+2e), S=10 species.
// Strategy: species-bucketed nodes (1024-padded segments) so each compute
// block is species-uniform; per-(c,s) contracted U*w records precomputed and
// staged in LDS; fp32 vector FMA throughout.
// ---------------------------------------------------------------------------

#define NN 10000
#define CC 128
#define SS 10
#define NPB 1024                 // nodes per contraction block (species-uniform)
#define MAXBLK 20                // >= floor(N/NPB)+S = 9+10
#define NPAD (MAXBLK*NPB)        // 20480 padded positions

// per-(c,s) record layout (floats):
//  [0,2916)   : 1o  [z][i][j][12] ; k=0..8 -> U3w_1o, [9]=U2w_1o, [10..11]=0
//  [2916,2944): U1w_1o [z][i] (27) + pad
//  [2944,3916): 0e  [i][j][12]   ; k=0..8 -> U3w_0e, [9]=U2w_0e
//  [3916,3928): U1w_0e [i] (9) + pad
#define U1_1O 2916
#define R0E   2944
#define U1_0E 3916
#define REC   3928

#define XSTR 37                  // per-thread x stash stride in LDS (odd mod 32 -> 2-way max)

// ws layout (floats)
#define OFF_UW   0                         // CC*SS*REC = 5,027,840
#define OFF_F0   5027840                   // CC*NPAD   = 2,621,440
#define OFF_F1   7649280                   // 3*CC*NPAD = 7,864,320
#define OFF_GATE 15513600                  // NPAD*256  = 5,242,880
#define OFF_ORD  20756480                  // NPAD ints
#define OFF_META (OFF_ORD + NPAD)          // 64 ints
// total = 20,777,024 floats = 83.1 MB

// ---------------- species bucketing ----------------
__global__ void k_hist(const int* __restrict__ sp, int* __restrict__ counts) {
    int n = blockIdx.x * 256 + threadIdx.x;
    if (n < NN) atomicAdd(&counts[sp[n]], 1);
}

__global__ void k_plan(const int* __restrict__ counts, int* __restrict__ cursor,
                       int* __restrict__ blk_sp) {
    if (threadIdx.x != 0) return;
    int pos = 0, b = 0;
    for (int s = 0; s < SS; ++s) {
        cursor[s] = pos;
        int nb = (counts[s] + NPB - 1) / NPB;
        for (int i = 0; i < nb; ++i) blk_sp[b++] = s;
        pos += nb * NPB;
    }
    for (; b < MAXBLK; ++b) blk_sp[b] = -1;
}

__global__ void k_scatter(const int* __restrict__ sp, int* __restrict__ cursor,
                          int* __restrict__ order) {
    int n = blockIdx.x * 256 + threadIdx.x;
    if (n < NN) {
        int p = atomicAdd(&cursor[sp[n]], 1);
        order[p] = n;
    }
}

// ---------------- precompute U*w records ----------------
__global__ __launch_bounds__(256) void k_prep(
    const float* __restrict__ u1_0e, const float* __restrict__ u2_0e, const float* __restrict__ u3_0e,
    const float* __restrict__ u1_1o, const float* __restrict__ u2_1o, const float* __restrict__ u3_1o,
    const float* __restrict__ w1_0e, const float* __restrict__ w2_0e, const float* __restrict__ w3_0e,
    const float* __restrict__ w1_1o, const float* __restrict__ w2_1o, const float* __restrict__ w3_1o,
    float* __restrict__ uw) {
    int b = blockIdx.x;            // b = c*SS + s
    int c = b / SS, s = b % SS;
    float* rec = uw + (size_t)b * REC;
    for (int idx = threadIdx.x; idx < REC; idx += 256) {
        float v = 0.f;
        if (idx < 2916) {
            int q = idx / 12, k = idx % 12;        // q = (z*9+i)*9+j
            if (k < 9) {
                const float* u = u3_1o + (q * 9 + k) * 30;
                const float* w = w3_1o + s * 30 * CC + c;
                float a = 0.f;
                for (int p = 0; p < 30; ++p) a += u[p] * w[p * CC];
                v = a;
            } else if (k == 9) {
                const float* u = u2_1o + q * 4;
                const float* w = w2_1o + s * 4 * CC + c;
                float a = 0.f;
                for (int p = 0; p < 4; ++p) a += u[p] * w[p * CC];
                v = a;
            }
        } else if (idx < R0E) {
            int e = idx - U1_1O;                   // [z][i]
            if (e < 27) v = u1_1o[e] * w1_1o[s * CC + c];
        } else if (idx < U1_0E) {
            int e = idx - R0E;
            int q = e / 12, k = e % 12;            // q = i*9+j
            if (k < 9) {
                const float* u = u3_0e + (q * 9 + k) * 23;
                const float* w = w3_0e + s * 23 * CC + c;
                float a = 0.f;
                for (int p = 0; p < 23; ++p) a += u[p] * w[p * CC];
                v = a;
            } else if (k == 9) {
                const float* u = u2_0e + q * 4;
                const float* w = w2_0e + s * 4 * CC + c;
                float a = 0.f;
                for (int p = 0; p < 4; ++p) a += u[p] * w[p * CC];
                v = a;
            }
        } else {
            int e = idx - U1_0E;
            if (e < 9) v = u1_0e[e] * w1_0e[s * CC + c];
        }
        rec[idx] = v;
    }
}

// ---------------- symmetric contraction ----------------
__global__ __launch_bounds__(256) void k_contract(
    const float* __restrict__ nf, const int* __restrict__ order,
    const int* __restrict__ blk_sp, const float* __restrict__ uw,
    float* __restrict__ f0t, float* __restrict__ f1t) {
    int b = blockIdx.x, c = blockIdx.y;
    int s = blk_sp[b];
    if (s < 0) return;                 // block-uniform exit
    __shared__ float rec[REC];
    __shared__ float xl[256 * XSTR];

    int tid = threadIdx.x;
    int pos0 = b * NPB + tid * 4;

    // per-thread 4 nodes (same species except never: segment is uniform)
    float x[4][9];
#pragma unroll
    for (int m = 0; m < 4; ++m) {
        int n = order[pos0 + m];
        if (n >= 0) {
            const float* r = nf + (size_t)n * 1152;
            x[m][0] = r[c];
#pragma unroll
            for (int j = 0; j < 3; ++j) x[m][1 + j] = r[128 + c * 3 + j];
#pragma unroll
            for (int j = 0; j < 5; ++j) x[m][4 + j] = r[512 + c * 5 + j];
        } else {
#pragma unroll
            for (int k = 0; k < 9; ++k) x[m][k] = 0.f;
        }
    }

    // stage the (c,s) record
    const float* src = uw + (size_t)(c * SS + s) * REC;
    for (int i = tid * 4; i < REC; i += 1024)
        *(float4*)&rec[i] = *(const float4*)&src[i];

    // stash x for dynamic-index (i/j) reads; register copy serves the k-loop
#pragma unroll
    for (int m = 0; m < 4; ++m)
#pragma unroll
        for (int k = 0; k < 9; ++k) xl[tid * XSTR + m * 9 + k] = x[m][k];

    __syncthreads();

    float o0[4] = {0.f, 0.f, 0.f, 0.f};
    float o1[4][3] = {{0.f,0.f,0.f},{0.f,0.f,0.f},{0.f,0.f,0.f},{0.f,0.f,0.f}};

    // ---- 1o (z = 0..2) ----
#pragma unroll
    for (int z = 0; z < 3; ++z) {
#pragma unroll 1
        for (int i = 0; i < 9; ++i) {
            float B[4] = {0.f, 0.f, 0.f, 0.f};
#pragma unroll 1
            for (int j = 0; j < 9; ++j) {
                const float* row = &rec[((z * 9 + i) * 9 + j) * 12];
                float4 a  = *(const float4*)row;
                float4 bq = *(const float4*)(row + 4);
                float4 cq = *(const float4*)(row + 8);
                float xj[4];
#pragma unroll
                for (int m = 0; m < 4; ++m) xj[m] = xl[tid * XSTR + m * 9 + j];
#pragma unroll
                for (int m = 0; m < 4; ++m) {
                    float t = cq.y;                       // U2w
                    t += a.x * x[m][0]; t += a.y * x[m][1];
                    t += a.z * x[m][2]; t += a.w * x[m][3];
                    t += bq.x * x[m][4]; t += bq.y * x[m][5];
                    t += bq.z * x[m][6]; t += bq.w * x[m][7];
                    t += cq.x * x[m][8];
                    B[m] += t * xj[m];
                }
            }
            float u1 = rec[U1_1O + z * 9 + i];
            float xi[4];
#pragma unroll
            for (int m = 0; m < 4; ++m) xi[m] = xl[tid * XSTR + m * 9 + i];
#pragma unroll
            for (int m = 0; m < 4; ++m) o1[m][z] += (u1 + B[m]) * xi[m];
        }
    }

    // ---- 0e ----
#pragma unroll 1
    for (int i = 0; i < 9; ++i) {
        float B[4] = {0.f, 0.f, 0.f, 0.f};
#pragma unroll 1
        for (int j = 0; j < 9; ++j) {
            const float* row = &rec[R0E + (i * 9 + j) * 12];
            float4 a  = *(const float4*)row;
            float4 bq = *(const float4*)(row + 4);
            float4 cq = *(const float4*)(row + 8);
            float xj[4];
#pragma unroll
            for (int m = 0; m < 4; ++m) xj[m] = xl[tid * XSTR + m * 9 + j];
#pragma unroll
            for (int m = 0; m < 4; ++m) {
                float t = cq.y;
                t += a.x * x[m][0]; t += a.y * x[m][1];
                t += a.z * x[m][2]; t += a.w * x[m][3];
                t += bq.x * x[m][4]; t += bq.y * x[m][5];
                t += bq.z * x[m][6]; t += bq.w * x[m][7];
                t += cq.x * x[m][8];
                B[m] += t * xj[m];
            }
        }
        float u1 = rec[U1_0E + i];
        float xi[4];
#pragma unroll
        for (int m = 0; m < 4; ++m) xi[m] = xl[tid * XSTR + m * 9 + i];
#pragma unroll
        for (int m = 0; m < 4; ++m) o0[m] += (u1 + B[m]) * xi[m];
    }

    // coalesced stores in sorted-position space (padding lanes write zeros)
    float4 v0 = {o0[0], o0[1], o0[2], o0[3]};
    *(float4*)&f0t[(size_t)c * NPAD + pos0] = v0;
#pragma unroll
    for (int z = 0; z < 3; ++z) {
        float4 v = {o1[0][z], o1[1][z], o1[2][z], o1[3][z]};
        *(float4*)&f1t[(size_t)(c * 3 + z) * NPAD + pos0] = v;
    }
}

// ---------------- gate: gate[pos,k] = bias + sum_c scal[pos,c]*gk[s,c,k] ----------------
#define SCSTR 132
__global__ __launch_bounds__(256) void k_gate(
    const float* __restrict__ f0t, const int* __restrict__ blk_sp,
    const float* __restrict__ gk, const float* __restrict__ gb,
    float* __restrict__ gate) {
    int b = blockIdx.x;                 // 64-position tile
    int s = blk_sp[b >> 4];             // 16 tiles per 1024-seg
    if (s < 0) return;
    int p0 = b * 64;
    __shared__ float scal[64 * SCSTR];  // [pl][c]
    for (int i = threadIdx.x; i < 8192; i += 256) {
        int c = i >> 6, pl = i & 63;    // 64 consecutive pos per c -> coalesced
        scal[pl * SCSTR + c] = f0t[(size_t)c * NPAD + p0 + pl];
    }
    __syncthreads();
    int k = threadIdx.x;
    float bias = gb[s * 256 + k];
    float acc[64];
#pragma unroll
    for (int pl = 0; pl < 64; ++pl) acc[pl] = bias;
    const float* w = gk + (size_t)s * CC * 256 + k;
#pragma unroll 1
    for (int cb = 0; cb < 128; cb += 4) {
        float w0 = w[(cb + 0) * 256], w1 = w[(cb + 1) * 256];
        float w2 = w[(cb + 2) * 256], w3 = w[(cb + 3) * 256];
#pragma unroll
        for (int pl = 0; pl < 64; ++pl) {
            float4 f = *(const float4*)&scal[pl * SCSTR + cb];
            acc[pl] += f.x * w0 + f.y * w1 + f.z * w2 + f.w * w3;
        }
    }
#pragma unroll
    for (int pl = 0; pl < 64; ++pl)
        gate[(size_t)(p0 + pl) * 256 + k] = acc[pl];
}

// ---------------- gated equivariant linear + output scatter ----------------
#define FGSTR 516
__global__ __launch_bounds__(512) void k_linear(
    const float* __restrict__ f0t, const float* __restrict__ f1t,
    const float* __restrict__ gate, const int* __restrict__ order,
    const int* __restrict__ blk_sp, const float* __restrict__ lin0,
    const float* __restrict__ lin1, float* __restrict__ out) {
    int b = blockIdx.x;
    int s = blk_sp[b >> 6];             // 64 tiles (16 pos) per 1024-seg
    if (s < 0) return;
    int p0 = b * 16;
    __shared__ float gl[16 * 256];
    __shared__ float fg[16 * FGSTR];    // [pl][part*128+c]
    __shared__ int ord[16];
    int t = threadIdx.x;
    if (t < 16) ord[t] = order[p0 + t];
    for (int i = t; i < 4096; i += 512) gl[i] = gate[(size_t)p0 * 256 + i];
    __syncthreads();
    for (int i = t; i < 8192; i += 512) {
        int cp = i >> 4, pl = i & 15;   // 16 consecutive pos -> 64B segments
        int part = cp >> 7, c = cp & 127;
        float v;
        if (part == 0)
            v = f0t[(size_t)c * NPAD + p0 + pl] * gl[pl * 256 + c];
        else
            v = f1t[(size_t)(c * 3 + part - 1) * NPAD + p0 + pl] * gl[pl * 256 + 128 + c];
        fg[pl * FGSTR + part * 128 + c] = v;
    }
    __syncthreads();
    int k = t & 127, part = t >> 7;     // wave-uniform part
    const float* lin = (part == 0) ? lin0 : lin1;
    float acc[16];
#pragma unroll
    for (int pl = 0; pl < 16; ++pl) acc[pl] = 0.f;
#pragma unroll 1
    for (int cb = 0; cb < 128; cb += 4) {
        float w0 = lin[(cb + 0) * CC + k], w1 = lin[(cb + 1) * CC + k];
        float w2 = lin[(cb + 2) * CC + k], w3 = lin[(cb + 3) * CC + k];
#pragma unroll
        for (int pl = 0; pl < 16; ++pl) {
            float4 f = *(const float4*)&fg[pl * FGSTR + part * 128 + cb];
            acc[pl] += f.x * w0 + f.y * w1 + f.z * w2 + f.w * w3;
        }
    }
    const float inv = 0.08838834764831845f;   // 1/sqrt(128)
    int kk = (part == 0) ? k : (128 + k * 3 + (part - 1));
#pragma unroll
    for (int pl = 0; pl < 16; ++pl) {
        int n = ord[pl];
        if (n >= 0) out[(size_t)n * 512 + kk] = acc[pl] * inv;
    }
}

// ---------------------------------------------------------------------------
extern "C" void kernel_launch(void* const* d_in, const int* in_sizes, int n_in,
                              void* d_out, int out_size, void* d_ws, size_t ws_size,
                              hipStream_t stream) {
    const float* nf    = (const float*)d_in[0];
    const int*   sp    = (const int*)  d_in[1];
    const float* u1_0e = (const float*)d_in[2];
    const float* u2_0e = (const float*)d_in[3];
    const float* u3_0e = (const float*)d_in[4];
    const float* u1_1o = (const float*)d_in[5];
    const float* u2_1o = (const float*)d_in[6];
    const float* u3_1o = (const float*)d_in[7];
    const float* w1_0e = (const float*)d_in[8];
    const float* w2_0e = (const float*)d_in[9];
    const float* w3_0e = (const float*)d_in[10];
    const float* w1_1o = (const float*)d_in[11];
    const float* w2_1o = (const float*)d_in[12];
    const float* w3_1o = (const float*)d_in[13];
    const float* gk    = (const float*)d_in[14];
    const float* gb    = (const float*)d_in[15];
    const float* lin0  = (const float*)d_in[16];
    const float* lin1  = (const float*)d_in[17];

    float* ws   = (float*)d_ws;
    float* uw   = ws + OFF_UW;
    float* f0t  = ws + OFF_F0;
    float* f1t  = ws + OFF_F1;
    float* gate = ws + OFF_GATE;
    int* order  = (int*)(ws + OFF_ORD);
    int* meta   = (int*)(ws + OFF_META);
    int* counts = meta;          // 10 (16 reserved)
    int* cursor = meta + 16;     // 10
    int* blk_sp = meta + 32;     // 20

    hipMemsetAsync(counts, 0, 16 * sizeof(int), stream);
    hipMemsetAsync(order, 0xFF, NPAD * sizeof(int), stream);

    k_hist<<<40, 256, 0, stream>>>(sp, counts);
    k_plan<<<1, 64, 0, stream>>>(counts, cursor, blk_sp);
    k_scatter<<<40, 256, 0, stream>>>(sp, cursor, order);
    k_prep<<<CC * SS, 256, 0, stream>>>(u1_0e, u2_0e, u3_0e, u1_1o, u2_1o, u3_1o,
                                        w1_0e, w2_0e, w3_0e, w1_1o, w2_1o, w3_1o, uw);
    dim3 gm(MAXBLK, CC);
    k_contract<<<gm, 256, 0, stream>>>(nf, order, blk_sp, uw, f0t, f1t);
    k_gate<<<NPAD / 64, 256, 0, stream>>>(f0t, blk_sp, gk, gb, gate);
    k_linear<<<NPAD / 16, 512, 0, stream>>>(f0t, f1t, gate, order, blk_sp, lin0, lin1,
                                            (float*)d_out);
}